// Round 5
// baseline (278.927 us; speedup 1.0000x reference)
//
#include <hip/hip_runtime.h>
#include <math.h>

#define NN 4096
#define DD 64
#define MM 266
#define MP 272
#define NORMZ 0.35355339059327379f   // 64^-0.25
#define RATIO 0.06131393394849658f   // 266^-0.5
#define EPSV 1e-4f
#define NEG_INF (-3.4e38f)
#define LSTR 64                       // LDS row stride in ushorts (128B; XOR-swizzled)
#define GSTR 320                      // gctxT row stride in ushorts

typedef __attribute__((ext_vector_type(8))) short bfrag;
typedef __attribute__((ext_vector_type(4))) float f32x4;

#define MFMA(a, b, c) __builtin_amdgcn_mfma_f32_16x16x32_bf16((a), (b), (c), 0, 0, 0)

// XOR bank swizzle: permutes 8-ushort blocks within a row; keeps b128 reads
// (col multiple of 8) and ushort4 stores (col multiple of 4) aligned.
__device__ inline int swz(int row, int col) {
    return row * LSTR + (col ^ ((((row >> 1) ^ (row >> 2)) & 7) << 3));
}

__device__ inline ushort bf16rne(float x) {
    union { float f; unsigned u; } c; c.f = x;
    unsigned r = c.u + 0x7FFFu + ((c.u >> 16) & 1u);
    return (ushort)(r >> 16);
}
__device__ inline float bf2f(ushort h) {
    union { unsigned u; float f; } c; c.u = ((unsigned)h) << 16;
    return c.f;
}
__device__ inline void splitf(float x, ushort& h, ushort& l) {
    h = bf16rne(x);
    l = bf16rne(x - bf2f(h));
}
// pack 8 scaled floats (two float4) into split bf16 fragments
__device__ inline void pack8(const float4& a, const float4& b, bfrag& H, bfrag& L) {
    ushort h, l;
    splitf(a.x, h, l); H[0] = (short)h; L[0] = (short)l;
    splitf(a.y, h, l); H[1] = (short)h; L[1] = (short)l;
    splitf(a.z, h, l); H[2] = (short)h; L[2] = (short)l;
    splitf(a.w, h, l); H[3] = (short)h; L[3] = (short)l;
    splitf(b.x, h, l); H[4] = (short)h; L[4] = (short)l;
    splitf(b.y, h, l); H[5] = (short)h; L[5] = (short)l;
    splitf(b.z, h, l); H[6] = (short)h; L[6] = (short)l;
    splitf(b.w, h, l); H[7] = (short)h; L[7] = (short)l;
}

// ---------------------------------------------------------------------------
// proj split: proj fp32 [266][64] -> pH/pL bf16 [272][64] (rows >=266 zero)
// ---------------------------------------------------------------------------
__global__ void proj_split(const float* __restrict__ proj,
                           ushort* __restrict__ pH, ushort* __restrict__ pL)
{
    int i = (blockIdx.x * 256 + threadIdx.x) * 4;   // 17*256*4 = 17408 = 272*64
    int m = i >> 6;
    float4 x = (m < MM) ? *(const float4*)(proj + i) : make_float4(0.f, 0.f, 0.f, 0.f);
    ushort h0, l0, h1, l1, h2, l2, h3, l3;
    splitf(x.x, h0, l0); splitf(x.y, h1, l1); splitf(x.z, h2, l2); splitf(x.w, h3, l3);
    *(ushort4*)(pH + i) = make_ushort4(h0, h1, h2, h3);
    *(ushort4*)(pL + i) = make_ushort4(l0, l1, l2, l3);
}

// ---------------------------------------------------------------------------
__global__ void reduce_max_kernel(const float* __restrict__ partmax,
                                  float* __restrict__ stab, int n)
{
    __shared__ float sm[256];
    const int t = threadIdx.x;
    float mx = NEG_INF;
    for (int i = t; i < n; i += 256) mx = fmaxf(mx, partmax[i]);
    sm[t] = mx;
    __syncthreads();
    for (int s = 128; s > 0; s >>= 1) {
        if (t < s) sm[t] = fmaxf(sm[t], sm[t + s]);
        __syncthreads();
    }
    if (t == 0) *stab = sm[0];
}

// ===========================================================================
// k-pass (round-2 structure: 256 threads, 4 waves, 2 blocks/CU) with
// XOR-swizzled LDS (LSTR=64).  Per 64-row subtile: dd = (NORMZ*k)@proj^T
// via split-bf16 MFMA, u = exp(dd - diag), block dd-max, ctx partial +=
// u^T@v via MFMA, kc partial += colsum(u).  vsum fused (reg acc + LDS
// reduce + 64 global atomics/block).  grid (16 nblocks, 32 heads).
// ===========================================================================
__launch_bounds__(256, 2)
__global__ void kpass(const float* __restrict__ kin, const float* __restrict__ vin,
                      const ushort* __restrict__ pjH, const ushort* __restrict__ pjL,
                      float* __restrict__ ctxP, float* __restrict__ kcP,
                      float* __restrict__ pmax, float* __restrict__ vsum)
{
    __shared__ ushort dataH[64 * LSTR], dataLo[64 * LSTR];  // dd-A source, then uT
    __shared__ ushort vTH[64 * LSTR], vTLo[64 * LSTR];      // [e][n] swizzled
    __shared__ ushort r2H[64 * LSTR], r2Lo[64 * LSTR];      // projL chunk [m_l][k]
    __shared__ float diagS[64];
    __shared__ float kcS[MP];
    __shared__ float redS[4];
    __shared__ float vredS[DD];

    const int t = threadIdx.x;
    const int w = t >> 6;
    const int lane = t & 63;
    const int l15 = lane & 15;
    const int q = lane >> 4;
    const int hd = blockIdx.y;
    const int nb = blockIdx.x;

    kcS[t] = 0.f;
    if (t < 16) kcS[256 + t] = 0.f;
    if (t < DD) vredS[t] = 0.f;

    const f32x4 zf = {0.f, 0.f, 0.f, 0.f};
    f32x4 cacc[4][4];
    f32x4 cacc4 = zf;
    #pragma unroll
    for (int c = 0; c < 4; ++c)
        #pragma unroll
        for (int e = 0; e < 4; ++e) cacc[c][e] = zf;
    float bmaxl = NEG_INF;
    float4 vacc = make_float4(0.f, 0.f, 0.f, 0.f);

    #pragma unroll 1
    for (int st = 0; st < 4; ++st) {
        const int n0 = (nb << 8) + (st << 6);
        __syncthreads();   // protect dataA/vT restage vs last chunk's ctx readers

        // ---- stage dataA (split, +diag) ----
        const float* kb = kin + ((size_t)hd * NN + n0) * DD;
        #pragma unroll
        for (int j = 0; j < 4; ++j) {
            int i = (t + (j << 8)) << 2;
            int r = i >> 6, cc = i & 63;
            float4 x = *(const float4*)(kb + i);
            float x0 = x.x * NORMZ, x1 = x.y * NORMZ, x2 = x.z * NORMZ, x3 = x.w * NORMZ;
            ushort h0, l0, h1, l1, h2, l2, h3, l3;
            splitf(x0, h0, l0); splitf(x1, h1, l1); splitf(x2, h2, l2); splitf(x3, h3, l3);
            *(ushort4*)&dataH[swz(r, cc)] = make_ushort4(h0, h1, h2, h3);
            *(ushort4*)&dataLo[swz(r, cc)] = make_ushort4(l0, l1, l2, l3);
            float ss = x0 * x0 + x1 * x1 + x2 * x2 + x3 * x3;
            #pragma unroll
            for (int d = 1; d < 16; d <<= 1) ss += __shfl_xor(ss, d);
            if (l15 == 0) diagS[r] = 0.5f * ss;
        }
        // ---- stage vT (split, transposed, swizzled) + vsum accumulate ----
        const float* vb = vin + ((size_t)hd * NN + n0) * DD;
        #pragma unroll
        for (int j = 0; j < 4; ++j) {
            int i = (t + (j << 8)) << 2;
            int n = i >> 6, e = i & 63;
            float4 x = *(const float4*)(vb + i);
            vacc.x += x.x; vacc.y += x.y; vacc.z += x.z; vacc.w += x.w;
            ushort h, l;
            splitf(x.x, h, l); vTH[swz(e + 0, n)] = h; vTLo[swz(e + 0, n)] = l;
            splitf(x.y, h, l); vTH[swz(e + 1, n)] = h; vTLo[swz(e + 1, n)] = l;
            splitf(x.z, h, l); vTH[swz(e + 2, n)] = h; vTLo[swz(e + 2, n)] = l;
            splitf(x.w, h, l); vTH[swz(e + 3, n)] = h; vTLo[swz(e + 3, n)] = l;
        }
        __syncthreads();

        // A-fragments for dd (held in regs; dataA region is reused as uT after)
        bfrag aH[2], aL[2];
        {
            const int row = (w << 4) + l15;
            aH[0] = *(const bfrag*)&dataH[swz(row, (q << 3))];
            aH[1] = *(const bfrag*)&dataH[swz(row, 32 + (q << 3))];
            aL[0] = *(const bfrag*)&dataLo[swz(row, (q << 3))];
            aL[1] = *(const bfrag*)&dataLo[swz(row, 32 + (q << 3))];
        }

        #pragma unroll
        for (int c = 0; c < 5; ++c) {
            const int mtiles = (c < 4) ? 4 : 1;
            const int m0 = c << 6;
            // stage projL chunk (r2)
            {
                const int tot = mtiles << 7;   // mtiles*16*64/8
                for (int idx = t; idx < tot; idx += 256) {
                    int i = idx << 3; int r = i >> 6, cc = i & 63;
                    *(uint4*)&r2H[swz(r, cc)] = *(const uint4*)(pjH + ((m0 + r) << 6) + cc);
                    *(uint4*)&r2Lo[swz(r, cc)] = *(const uint4*)(pjL + ((m0 + r) << 6) + cc);
                }
            }
            __syncthreads();   // B1: projL ready; prior ctx readers of uT done

            // dd MFMAs
            f32x4 dd4[4];
            #pragma unroll
            for (int mt = 0; mt < 4; ++mt) {
                if (mt >= mtiles) break;
                const int mrow = (mt << 4) + l15;
                bfrag bH0 = *(const bfrag*)&r2H[swz(mrow, (q << 3))];
                bfrag bH1 = *(const bfrag*)&r2H[swz(mrow, 32 + (q << 3))];
                bfrag bL0 = *(const bfrag*)&r2Lo[swz(mrow, (q << 3))];
                bfrag bL1 = *(const bfrag*)&r2Lo[swz(mrow, 32 + (q << 3))];
                f32x4 a = zf;
                a = MFMA(aH[0], bL0, a);
                a = MFMA(aH[1], bL1, a);
                a = MFMA(aL[0], bH0, a);
                a = MFMA(aL[1], bH1, a);
                a = MFMA(aH[0], bH0, a);
                a = MFMA(aH[1], bH1, a);
                dd4[mt] = a;
            }
            // exp + max + kc + scatter uT into data region
            #pragma unroll
            for (int mt = 0; mt < 4; ++mt) {
                if (mt >= mtiles) break;
                const int mg = m0 + (mt << 4) + l15;
                const bool valid = (mg < MM);
                ushort uh[4], ul[4];
                float csum = 0.f;
                #pragma unroll
                for (int reg = 0; reg < 4; ++reg) {
                    float dv = dd4[mt][reg];
                    float u = 0.f;
                    if (valid) {
                        bmaxl = fmaxf(bmaxl, dv);
                        u = __expf(dv - diagS[(w << 4) + (q << 2) + reg]);
                    }
                    csum += u;
                    splitf(u, uh[reg], ul[reg]);
                }
                *(ushort4*)&dataH[swz((mt << 4) + l15, (w << 4) + (q << 2))] =
                    make_ushort4(uh[0], uh[1], uh[2], uh[3]);
                *(ushort4*)&dataLo[swz((mt << 4) + l15, (w << 4) + (q << 2))] =
                    make_ushort4(ul[0], ul[1], ul[2], ul[3]);
                csum += __shfl_xor(csum, 16);
                csum += __shfl_xor(csum, 32);
                if (q == 0) atomicAdd(&kcS[mg], csum);
            }
            __syncthreads();   // B2: uT complete

            // ctx MFMAs: D[m][e] += uT . v
            if (c < 4) {
                const int mrow = (w << 4) + l15;
                bfrag uH0 = *(const bfrag*)&dataH[swz(mrow, (q << 3))];
                bfrag uH1 = *(const bfrag*)&dataH[swz(mrow, 32 + (q << 3))];
                bfrag uL0 = *(const bfrag*)&dataLo[swz(mrow, (q << 3))];
                bfrag uL1 = *(const bfrag*)&dataLo[swz(mrow, 32 + (q << 3))];
                #pragma unroll
                for (int et = 0; et < 4; ++et) {
                    const int erow = (et << 4) + l15;
                    bfrag vH0 = *(const bfrag*)&vTH[swz(erow, (q << 3))];
                    bfrag vH1 = *(const bfrag*)&vTH[swz(erow, 32 + (q << 3))];
                    bfrag vL0 = *(const bfrag*)&vTLo[swz(erow, (q << 3))];
                    bfrag vL1 = *(const bfrag*)&vTLo[swz(erow, 32 + (q << 3))];
                    f32x4 a = cacc[c][et];
                    a = MFMA(uH0, vL0, a);
                    a = MFMA(uH1, vL1, a);
                    a = MFMA(uL0, vH0, a);
                    a = MFMA(uL1, vH1, a);
                    a = MFMA(uH0, vH0, a);
                    a = MFMA(uH1, vH1, a);
                    cacc[c][et] = a;
                }
            } else {
                const int mrow = l15;   // m-tile 16 uses rows 0..15 of uT buffer
                bfrag uH0 = *(const bfrag*)&dataH[swz(mrow, (q << 3))];
                bfrag uH1 = *(const bfrag*)&dataH[swz(mrow, 32 + (q << 3))];
                bfrag uL0 = *(const bfrag*)&dataLo[swz(mrow, (q << 3))];
                bfrag uL1 = *(const bfrag*)&dataLo[swz(mrow, 32 + (q << 3))];
                const int erow = (w << 4) + l15;   // wave w -> e-tile w
                bfrag vH0 = *(const bfrag*)&vTH[swz(erow, (q << 3))];
                bfrag vH1 = *(const bfrag*)&vTH[swz(erow, 32 + (q << 3))];
                bfrag vL0 = *(const bfrag*)&vTLo[swz(erow, (q << 3))];
                bfrag vL1 = *(const bfrag*)&vTLo[swz(erow, 32 + (q << 3))];
                f32x4 a = cacc4;
                a = MFMA(uH0, vL0, a);
                a = MFMA(uH1, vL1, a);
                a = MFMA(uL0, vH0, a);
                a = MFMA(uL1, vH1, a);
                a = MFMA(uH0, vH0, a);
                a = MFMA(uH1, vH1, a);
                cacc4 = a;
            }
        }
    }

    __syncthreads();
    // block dd-max + vsum LDS reduce
    {
        float bm = bmaxl;
        #pragma unroll
        for (int d = 1; d < 64; d <<= 1) bm = fmaxf(bm, __shfl_xor(bm, d));
        if (lane == 0) redS[w] = bm;
    }
    {
        const int e0 = (t << 2) & 63;
        atomicAdd(&vredS[e0 + 0], vacc.x);
        atomicAdd(&vredS[e0 + 1], vacc.y);
        atomicAdd(&vredS[e0 + 2], vacc.z);
        atomicAdd(&vredS[e0 + 3], vacc.w);
    }
    __syncthreads();
    if (t == 0) pmax[hd * 16 + nb] = fmaxf(fmaxf(redS[0], redS[1]), fmaxf(redS[2], redS[3]));
    if (t < DD) atomicAdd(&vsum[hd * DD + t], vredS[t]);
    // kc partial
    for (int m = t; m < MP; m += 256) kcP[(size_t)(hd * 16 + nb) * MP + m] = kcS[m];
    // ctx partial
    float* cp = ctxP + (size_t)(hd * 16 + nb) * MP * DD;
    #pragma unroll
    for (int c = 0; c < 4; ++c) {
        const int mbase = (c << 6) + (w << 4) + (q << 2);
        #pragma unroll
        for (int et = 0; et < 4; ++et)
            #pragma unroll
            for (int reg = 0; reg < 4; ++reg)
                cp[(mbase + reg) * DD + (et << 4) + l15] = cacc[c][et][reg];
    }
    #pragma unroll
    for (int reg = 0; reg < 4; ++reg)
        cp[(256 + (q << 2) + reg) * DD + (w << 4) + l15] = cacc4[reg];
}

// ===========================================================================
// ctx reduce: sum 16 partials, scale by Asc=RATIO*e^-stab, add REPS*vsum,
// split to bf16, write TRANSPOSED gctxT[hd][e][m] (64 e-rows/head), and write
// the column-sum vector kcF as FLOAT (denominator computed in VALU in qpass).
// grid (17 m-tiles, 32 heads)
// ===========================================================================
__global__ void ctx_reduce(const float* __restrict__ ctxP, const float* __restrict__ kcP,
                           const float* __restrict__ vsum, const float* __restrict__ stabp,
                           ushort* __restrict__ gH, ushort* __restrict__ gL,
                           float* __restrict__ kcF)
{
    __shared__ ushort hiT[64][20], loT[64][20];
    const int t = threadIdx.x, mt = blockIdx.x, hd = blockIdx.y;
    const float Asc = RATIO * __expf(-*stabp);
    const float REPS = RATIO * EPSV;
    const int e = t & 63, mq = t >> 6;
    const float vs = vsum[hd * DD + e];
    #pragma unroll
    for (int i = 0; i < 4; ++i) {
        const int ml = mq * 4 + i;
        const int m = mt * 16 + ml;
        float s = 0.f;
        for (int nbk = 0; nbk < 16; ++nbk)
            s += ctxP[((size_t)(hd * 16 + nbk) * MP + m) * DD + e];
        float val = Asc * s + REPS * vs;
        ushort h, l; splitf(val, h, l);
        hiT[e][ml] = h; loT[e][ml] = l;
    }
    __syncthreads();
    {
        const int i = t * 4, e2 = i >> 4, cc = i & 15;
        ushort4 hv = make_ushort4(hiT[e2][cc], hiT[e2][cc + 1], hiT[e2][cc + 2], hiT[e2][cc + 3]);
        ushort4 lv = make_ushort4(loT[e2][cc], loT[e2][cc + 1], loT[e2][cc + 2], loT[e2][cc + 3]);
        *(ushort4*)(gH + ((size_t)hd * 64 + e2) * GSTR + mt * 16 + cc) = hv;
        *(ushort4*)(gL + ((size_t)hd * 64 + e2) * GSTR + mt * 16 + cc) = lv;
    }
    if (t < 16) {
        const int m = mt * 16 + t;
        float s = 0.f;
        for (int nbk = 0; nbk < 16; ++nbk) s += kcP[(size_t)(hd * 16 + nbk) * MP + m];
        kcF[hd * MP + m] = Asc * s + ((m < MM) ? REPS * (float)NN : 0.f);
    }
}

// ===========================================================================
// q-pass (round-2 v3) with XOR-swizzled LDS (LSTR=64): A-fragments + diag
// direct from global; phase 1: proj chunks LDS-staged, dd via MFMA; phase 2:
// rowmax + qp + VALU denominator; phase 3: qp scatter + ctxT chunks staged,
// out MFMAs.  LDS 32.9 KB -> 4 blocks/CU.  grid (64 nblocks, 32 heads).
// ===========================================================================
__launch_bounds__(256, 4)
__global__ void qpass(const float* __restrict__ qin,
                      const ushort* __restrict__ pjH, const ushort* __restrict__ pjL,
                      const ushort* __restrict__ gH, const ushort* __restrict__ gL,
                      const float* __restrict__ kcF,
                      float* __restrict__ outp)
{
    __shared__ ushort bPH[64 * LSTR], bPL[64 * LSTR];   // proj chunk, then qpA
    __shared__ ushort bQH[64 * LSTR], bQL[64 * LSTR];   // ctxT chunk

    const int t = threadIdx.x;
    const int w = t >> 6;
    const int lane = t & 63;
    const int l15 = lane & 15;
    const int q = lane >> 4;
    const int hd = blockIdx.y;
    const int n0 = blockIdx.x << 6;

    // ---- A-fragments + diag, direct from global (once per block) ----
    const float* qb = qin + ((size_t)hd * NN + n0) * DD;
    const int row = (w << 4) + l15;
    float4 x0 = *(const float4*)(qb + (row << 6) + (q << 3));
    float4 x1 = *(const float4*)(qb + (row << 6) + (q << 3) + 4);
    float4 x2 = *(const float4*)(qb + (row << 6) + 32 + (q << 3));
    float4 x3 = *(const float4*)(qb + (row << 6) + 32 + (q << 3) + 4);
    x0.x *= NORMZ; x0.y *= NORMZ; x0.z *= NORMZ; x0.w *= NORMZ;
    x1.x *= NORMZ; x1.y *= NORMZ; x1.z *= NORMZ; x1.w *= NORMZ;
    x2.x *= NORMZ; x2.y *= NORMZ; x2.z *= NORMZ; x2.w *= NORMZ;
    x3.x *= NORMZ; x3.y *= NORMZ; x3.z *= NORMZ; x3.w *= NORMZ;
    float ss = x0.x*x0.x + x0.y*x0.y + x0.z*x0.z + x0.w*x0.w
             + x1.x*x1.x + x1.y*x1.y + x1.z*x1.z + x1.w*x1.w
             + x2.x*x2.x + x2.y*x2.y + x2.z*x2.z + x2.w*x2.w
             + x3.x*x3.x + x3.y*x3.y + x3.z*x3.z + x3.w*x3.w;
    ss += __shfl_xor(ss, 16);
    ss += __shfl_xor(ss, 32);
    float dg[4];
    #pragma unroll
    for (int r = 0; r < 4; ++r) dg[r] = 0.5f * __shfl(ss, (q << 2) + r);
    bfrag aH[2], aL[2];
    pack8(x0, x1, aH[0], aL[0]);
    pack8(x2, x3, aH[1], aL[1]);

    const f32x4 zf = {0.f, 0.f, 0.f, 0.f};
    f32x4 ddq[17];

    // ---- phase 1: dd for all 272 m (proj chunks via LDS) ----
    #pragma unroll
    for (int c = 0; c < 5; ++c) {
        const int mtiles = (c < 4) ? 4 : 1;
        const int m0 = c << 6;
        __syncthreads();   // prior chunk's fragment readers done
        {
            const int tot = mtiles << 7;
            for (int idx = t; idx < tot; idx += 256) {
                int i = idx << 3; int r = i >> 6, cc = i & 63;
                *(uint4*)&bPH[swz(r, cc)] = *(const uint4*)(pjH + ((m0 + r) << 6) + cc);
                *(uint4*)&bPL[swz(r, cc)] = *(const uint4*)(pjL + ((m0 + r) << 6) + cc);
            }
        }
        __syncthreads();
        #pragma unroll
        for (int mt = 0; mt < 4; ++mt) {
            if (mt >= mtiles) break;
            const int mrow = (mt << 4) + l15;
            bfrag bH0 = *(const bfrag*)&bPH[swz(mrow, (q << 3))];
            bfrag bH1 = *(const bfrag*)&bPH[swz(mrow, 32 + (q << 3))];
            bfrag bL0 = *(const bfrag*)&bPL[swz(mrow, (q << 3))];
            bfrag bL1 = *(const bfrag*)&bPL[swz(mrow, 32 + (q << 3))];
            f32x4 a = zf;
            a = MFMA(aH[0], bL0, a);
            a = MFMA(aH[1], bL1, a);
            a = MFMA(aL[0], bH0, a);
            a = MFMA(aL[1], bH1, a);
            a = MFMA(aH[0], bH0, a);
            a = MFMA(aH[1], bH1, a);
            ddq[c * 4 + mt] = a;
        }
    }

    // ---- phase 2: rowmax + qp + denominator (registers only) ----
    float rmax[4];
    #pragma unroll
    for (int reg = 0; reg < 4; ++reg) {
        float mx = NEG_INF;
        #pragma unroll
        for (int ti = 0; ti < 17; ++ti) {
            bool valid = (ti < 16) || (l15 < 10);
            if (valid) mx = fmaxf(mx, ddq[ti][reg]);
        }
        #pragma unroll
        for (int d = 1; d < 16; d <<= 1) mx = fmaxf(mx, __shfl_xor(mx, d));
        rmax[reg] = mx;
    }
    #pragma unroll
    for (int ti = 0; ti < 17; ++ti) {
        #pragma unroll
        for (int reg = 0; reg < 4; ++reg) {
            bool valid = (ti < 16) || (l15 < 10);
            float e = 0.f;
            if (valid)
                e = RATIO * (__expf(ddq[ti][reg] - dg[reg] - rmax[reg]) + EPSV);
            ddq[ti][reg] = e;
        }
    }
    // denominator: den[n] = sum_m qp[n][m]*kc[m], lands in the owning lanes
    float dinv[4];
    {
        const float* kcb = kcF + hd * MP;
        float den[4] = {0.f, 0.f, 0.f, 0.f};
        #pragma unroll
        for (int ti = 0; ti < 17; ++ti) {
            float kv = kcb[(ti << 4) + l15];
            #pragma unroll
            for (int reg = 0; reg < 4; ++reg) den[reg] += ddq[ti][reg] * kv;
        }
        #pragma unroll
        for (int reg = 0; reg < 4; ++reg) {
            #pragma unroll
            for (int d = 1; d < 16; d <<= 1) den[reg] += __shfl_xor(den[reg], d);
            dinv[reg] = 1.f / den[reg];
        }
    }

    // ---- phase 3: out = qp @ ctxT (qp chunk in bufP, ctxT chunk in bufQ) ----
    f32x4 oacc[4];
    #pragma unroll
    for (int et = 0; et < 4; ++et) oacc[et] = zf;

    #pragma unroll
    for (int c = 0; c < 5; ++c) {
        const int mtiles = (c < 4) ? 4 : 1;
        __syncthreads();   // prior chunk's bufP/bufQ readers done
        // scatter qp chunk (own rows only)
        #pragma unroll
        for (int mt = 0; mt < 4; ++mt) {
            if (mt >= mtiles) break;
            const int ml = (mt << 4) + l15;
            #pragma unroll
            for (int reg = 0; reg < 4; ++reg) {
                ushort hh, ll; splitf(ddq[c * 4 + mt][reg], hh, ll);
                bPH[swz((w << 4) + (q << 2) + reg, ml)] = hh;
                bPL[swz((w << 4) + (q << 2) + reg, ml)] = ll;
            }
        }
        if (c == 4) {   // zero-pad qp cols 16..31 (K-step padding)
            const int rown = (w << 4) + l15;
            *(ushort4*)&bPH[swz(rown, 16 + (q << 2))] = make_ushort4(0, 0, 0, 0);
            *(ushort4*)&bPL[swz(rown, 16 + (q << 2))] = make_ushort4(0, 0, 0, 0);
        }
        // stage ctxT chunk [64 e][64 m] (coalesced)
        {
            for (int idx = t; idx < 512; idx += 256) {
                int i = idx << 3; int e = i >> 6, mm = i & 63;
                *(uint4*)&bQH[swz(e, mm)] =
                    *(const uint4*)(gH + ((size_t)hd * 64 + e) * GSTR + (c << 6) + mm);
                *(uint4*)&bQL[swz(e, mm)] =
                    *(const uint4*)(gL + ((size_t)hd * 64 + e) * GSTR + (c << 6) + mm);
            }
        }
        __syncthreads();
        const int arow = (w << 4) + l15;
        bfrag pH0 = *(const bfrag*)&bPH[swz(arow, (q << 3))];
        bfrag pL0 = *(const bfrag*)&bPL[swz(arow, (q << 3))];
        bfrag pH1, pL1;
        if (c < 4) {
            pH1 = *(const bfrag*)&bPH[swz(arow, 32 + (q << 3))];
            pL1 = *(const bfrag*)&bPL[swz(arow, 32 + (q << 3))];
        }
        #pragma unroll
        for (int et = 0; et < 4; ++et) {
            const int erow = (et << 4) + l15;
            bfrag cH0 = *(const bfrag*)&bQH[swz(erow, (q << 3))];
            bfrag cL0 = *(const bfrag*)&bQL[swz(erow, (q << 3))];
            f32x4 a = oacc[et];
            a = MFMA(pH0, cL0, a);
            a = MFMA(pL0, cH0, a);
            a = MFMA(pH0, cH0, a);
            if (c < 4) {
                bfrag cH1 = *(const bfrag*)&bQH[swz(erow, 32 + (q << 3))];
                bfrag cL1 = *(const bfrag*)&bQL[swz(erow, 32 + (q << 3))];
                a = MFMA(pH1, cL1, a);
                a = MFMA(pL1, cH1, a);
                a = MFMA(pH1, cH1, a);
            }
            oacc[et] = a;
        }
    }

    // ---- epilogue: scale by 1/den (already in the owning lanes) ----
    float* ob = outp + ((size_t)hd * NN + n0) * DD;
    #pragma unroll
    for (int et = 0; et < 4; ++et)
        #pragma unroll
        for (int reg = 0; reg < 4; ++reg)
            ob[((w << 4) + (q << 2) + reg) * DD + (et << 4) + l15] = oacc[et][reg] * dinv[reg];
}

// ---------------------------------------------------------------------------
extern "C" void kernel_launch(void* const* d_in, const int* in_sizes, int n_in,
                              void* d_out, int out_size, void* d_ws, size_t ws_size,
                              hipStream_t stream)
{
    const float* q = (const float*)d_in[0];
    const float* k = (const float*)d_in[1];
    const float* v = (const float*)d_in[2];
    const float* proj = (const float*)d_in[3];
    float* out = (float*)d_out;
    char* ws = (char*)d_ws;

    ushort* gH  = (ushort*)(ws);                    // 32*64*320*2 = 1,310,720 B
    ushort* gL  = (ushort*)(ws + 1310720);          // 1,310,720 B
    float*  vsm = (float*)(ws + 2621440);           // 8,192 B
    ushort* pH  = (ushort*)(ws + 2629632);          // 34,816 B
    ushort* pL  = (ushort*)(ws + 2664448);          // 34,816 B
    float*  kcF = (float*)(ws + 2699264);           // 34,816 B
    float*  ctxP= (float*)(ws + 2734080);           // 512*272*64*4 = 35,651,584 B
    float*  kcP = (float*)(ws + 38385664);          // 557,056 B
    float*  pmax= (float*)(ws + 38942720);          // 2,048 B
    float*  stab= (float*)(ws + 38944768);          // 4 B

    hipMemsetAsync(ws, 0, 2629632, stream);         // gH, gL, vsum

    proj_split<<<dim3(17), 256, 0, stream>>>(proj, pH, pL);
    kpass<<<dim3(16, 32), 256, 0, stream>>>(k, v, pH, pL, ctxP, kcP, pmax, vsm);
    reduce_max_kernel<<<1, 256, 0, stream>>>(pmax, stab, 512);
    ctx_reduce<<<dim3(17, 32), 256, 0, stream>>>(ctxP, kcP, vsm, stab, gH, gL, kcF);
    qpass<<<dim3(64, 32), 256, 0, stream>>>(q, pH, pL, gH, gL, kcF, out);
}

// Round 6
// 255.638 us; speedup vs baseline: 1.0911x; 1.0911x over previous
//
#include <hip/hip_runtime.h>
#include <math.h>

#define NN 4096
#define DD 64
#define MM 266
#define MP 272
#define NORMZ 0.35355339059327379f   // 64^-0.25
#define RATIO 0.06131393394849658f   // 266^-0.5
#define EPSV 1e-4f
#define NEG_INF (-3.4e38f)
#define LSTR 72                       // plain LDS row stride in ushorts (144B)
#define VSTR 64                       // vT swizzled stride (128B)
#define GSTR 320                      // gctxT row stride in ushorts

typedef __attribute__((ext_vector_type(8))) short bfrag;
typedef __attribute__((ext_vector_type(4))) float f32x4;

#define MFMA(a, b, c) __builtin_amdgcn_mfma_f32_16x16x32_bf16((a), (b), (c), 0, 0, 0)

// vT-only XOR swizzle (round-5 function, kept ONLY on the one 16-way-conflict
// buffer to avoid the register-pressure spill round 5 hit when applied
// everywhere).  Permutes 8-ushort blocks; b128 reads stay 16B-aligned.
__device__ inline int swzV(int row, int col) {
    return row * VSTR + (col ^ ((((row >> 1) ^ (row >> 2)) & 7) << 3));
}

__device__ inline ushort bf16rne(float x) {
    union { float f; unsigned u; } c; c.f = x;
    unsigned r = c.u + 0x7FFFu + ((c.u >> 16) & 1u);
    return (ushort)(r >> 16);
}
__device__ inline float bf2f(ushort h) {
    union { unsigned u; float f; } c; c.u = ((unsigned)h) << 16;
    return c.f;
}
__device__ inline void splitf(float x, ushort& h, ushort& l) {
    h = bf16rne(x);
    l = bf16rne(x - bf2f(h));
}
// pack 8 scaled floats (two float4) into split bf16 fragments
__device__ inline void pack8(const float4& a, const float4& b, bfrag& H, bfrag& L) {
    ushort h, l;
    splitf(a.x, h, l); H[0] = (short)h; L[0] = (short)l;
    splitf(a.y, h, l); H[1] = (short)h; L[1] = (short)l;
    splitf(a.z, h, l); H[2] = (short)h; L[2] = (short)l;
    splitf(a.w, h, l); H[3] = (short)h; L[3] = (short)l;
    splitf(b.x, h, l); H[4] = (short)h; L[4] = (short)l;
    splitf(b.y, h, l); H[5] = (short)h; L[5] = (short)l;
    splitf(b.z, h, l); H[6] = (short)h; L[6] = (short)l;
    splitf(b.w, h, l); H[7] = (short)h; L[7] = (short)l;
}

// ---------------------------------------------------------------------------
// proj split: proj fp32 [266][64] -> pH/pL bf16 [272][64] (rows >=266 zero)
// ---------------------------------------------------------------------------
__global__ void proj_split(const float* __restrict__ proj,
                           ushort* __restrict__ pH, ushort* __restrict__ pL)
{
    int i = (blockIdx.x * 256 + threadIdx.x) * 4;   // 17*256*4 = 17408 = 272*64
    int m = i >> 6;
    float4 x = (m < MM) ? *(const float4*)(proj + i) : make_float4(0.f, 0.f, 0.f, 0.f);
    ushort h0, l0, h1, l1, h2, l2, h3, l3;
    splitf(x.x, h0, l0); splitf(x.y, h1, l1); splitf(x.z, h2, l2); splitf(x.w, h3, l3);
    *(ushort4*)(pH + i) = make_ushort4(h0, h1, h2, h3);
    *(ushort4*)(pL + i) = make_ushort4(l0, l1, l2, l3);
}

// ===========================================================================
// k-pass (round-2 structure: 256 threads, 4 waves, 2 blocks/CU, LSTR=72
// everywhere EXCEPT vT which uses the swizzled VSTR layout — the scalar
// transpose store was the lone 16-way bank-conflict site).  Per 64-row
// subtile: dd = (NORMZ*k)@proj^T via split-bf16 MFMA, u = exp(dd - diag),
// block dd-max, ctx partial += u^T@v via MFMA, kc partial += colsum(u).
// vsum fused (reg acc + LDS reduce + 64 global atomics/block).
// grid (16 nblocks, 32 heads).
// ===========================================================================
__launch_bounds__(256, 2)
__global__ void kpass(const float* __restrict__ kin, const float* __restrict__ vin,
                      const ushort* __restrict__ pjH, const ushort* __restrict__ pjL,
                      float* __restrict__ ctxP, float* __restrict__ kcP,
                      float* __restrict__ pmax, float* __restrict__ vsum)
{
    __shared__ ushort dataH[64 * LSTR], dataLo[64 * LSTR];  // dd-A source, then uT
    __shared__ ushort vTH[64 * VSTR], vTLo[64 * VSTR];      // [e][n], swizzled
    __shared__ ushort r2H[64 * LSTR], r2Lo[64 * LSTR];      // projL chunk [m_l][k]
    __shared__ float diagS[64];
    __shared__ float kcS[MP];
    __shared__ float redS[4];
    __shared__ float vredS[DD];

    const int t = threadIdx.x;
    const int w = t >> 6;
    const int lane = t & 63;
    const int l15 = lane & 15;
    const int q = lane >> 4;
    const int hd = blockIdx.y;
    const int nb = blockIdx.x;

    kcS[t] = 0.f;
    if (t < 16) kcS[256 + t] = 0.f;
    if (t < DD) vredS[t] = 0.f;

    const f32x4 zf = {0.f, 0.f, 0.f, 0.f};
    f32x4 cacc[4][4];
    f32x4 cacc4 = zf;
    #pragma unroll
    for (int c = 0; c < 4; ++c)
        #pragma unroll
        for (int e = 0; e < 4; ++e) cacc[c][e] = zf;
    float bmaxl = NEG_INF;
    float4 vacc = make_float4(0.f, 0.f, 0.f, 0.f);

    #pragma unroll 1
    for (int st = 0; st < 4; ++st) {
        const int n0 = (nb << 8) + (st << 6);
        __syncthreads();   // protect dataA/vT restage vs last chunk's ctx readers

        // ---- stage dataA (split, +diag) ----
        const float* kb = kin + ((size_t)hd * NN + n0) * DD;
        #pragma unroll
        for (int j = 0; j < 4; ++j) {
            int i = (t + (j << 8)) << 2;
            int r = i >> 6, cc = i & 63;
            float4 x = *(const float4*)(kb + i);
            float x0 = x.x * NORMZ, x1 = x.y * NORMZ, x2 = x.z * NORMZ, x3 = x.w * NORMZ;
            ushort h0, l0, h1, l1, h2, l2, h3, l3;
            splitf(x0, h0, l0); splitf(x1, h1, l1); splitf(x2, h2, l2); splitf(x3, h3, l3);
            *(ushort4*)&dataH[r * LSTR + cc] = make_ushort4(h0, h1, h2, h3);
            *(ushort4*)&dataLo[r * LSTR + cc] = make_ushort4(l0, l1, l2, l3);
            float ss = x0 * x0 + x1 * x1 + x2 * x2 + x3 * x3;
            #pragma unroll
            for (int d = 1; d < 16; d <<= 1) ss += __shfl_xor(ss, d);
            if (l15 == 0) diagS[r] = 0.5f * ss;
        }
        // ---- stage vT (split, transposed, swizzled) + vsum accumulate ----
        const float* vb = vin + ((size_t)hd * NN + n0) * DD;
        #pragma unroll
        for (int j = 0; j < 4; ++j) {
            int i = (t + (j << 8)) << 2;
            int n = i >> 6, e = i & 63;
            float4 x = *(const float4*)(vb + i);
            vacc.x += x.x; vacc.y += x.y; vacc.z += x.z; vacc.w += x.w;
            ushort h, l;
            splitf(x.x, h, l); vTH[swzV(e + 0, n)] = h; vTLo[swzV(e + 0, n)] = l;
            splitf(x.y, h, l); vTH[swzV(e + 1, n)] = h; vTLo[swzV(e + 1, n)] = l;
            splitf(x.z, h, l); vTH[swzV(e + 2, n)] = h; vTLo[swzV(e + 2, n)] = l;
            splitf(x.w, h, l); vTH[swzV(e + 3, n)] = h; vTLo[swzV(e + 3, n)] = l;
        }
        __syncthreads();

        // A-fragments for dd (held in regs; dataA region is reused as uT after)
        bfrag aH[2], aL[2];
        {
            const int row = (w << 4) + l15;
            aH[0] = *(const bfrag*)&dataH[row * LSTR + (q << 3)];
            aH[1] = *(const bfrag*)&dataH[row * LSTR + 32 + (q << 3)];
            aL[0] = *(const bfrag*)&dataLo[row * LSTR + (q << 3)];
            aL[1] = *(const bfrag*)&dataLo[row * LSTR + 32 + (q << 3)];
        }

        #pragma unroll
        for (int c = 0; c < 5; ++c) {
            const int mtiles = (c < 4) ? 4 : 1;
            const int m0 = c << 6;
            // stage projL chunk (r2)
            {
                const int tot = mtiles << 7;   // mtiles*16*64/8
                for (int idx = t; idx < tot; idx += 256) {
                    int i = idx << 3; int r = i >> 6, cc = i & 63;
                    *(uint4*)&r2H[r * LSTR + cc] = *(const uint4*)(pjH + ((m0 + r) << 6) + cc);
                    *(uint4*)&r2Lo[r * LSTR + cc] = *(const uint4*)(pjL + ((m0 + r) << 6) + cc);
                }
            }
            __syncthreads();   // B1: projL ready; prior ctx readers of uT done

            // dd MFMAs
            f32x4 dd4[4];
            #pragma unroll
            for (int mt = 0; mt < 4; ++mt) {
                if (mt >= mtiles) break;
                const int mrow = (mt << 4) + l15;
                bfrag bH0 = *(const bfrag*)&r2H[mrow * LSTR + (q << 3)];
                bfrag bH1 = *(const bfrag*)&r2H[mrow * LSTR + 32 + (q << 3)];
                bfrag bL0 = *(const bfrag*)&r2Lo[mrow * LSTR + (q << 3)];
                bfrag bL1 = *(const bfrag*)&r2Lo[mrow * LSTR + 32 + (q << 3)];
                f32x4 a = zf;
                a = MFMA(aH[0], bL0, a);
                a = MFMA(aH[1], bL1, a);
                a = MFMA(aL[0], bH0, a);
                a = MFMA(aL[1], bH1, a);
                a = MFMA(aH[0], bH0, a);
                a = MFMA(aH[1], bH1, a);
                dd4[mt] = a;
            }
            // exp + max + kc + scatter uT into data region
            #pragma unroll
            for (int mt = 0; mt < 4; ++mt) {
                if (mt >= mtiles) break;
                const int mg = m0 + (mt << 4) + l15;
                const bool valid = (mg < MM);
                ushort uh[4], ul[4];
                float csum = 0.f;
                #pragma unroll
                for (int reg = 0; reg < 4; ++reg) {
                    float dv = dd4[mt][reg];
                    float u = 0.f;
                    if (valid) {
                        bmaxl = fmaxf(bmaxl, dv);
                        u = __expf(dv - diagS[(w << 4) + (q << 2) + reg]);
                    }
                    csum += u;
                    splitf(u, uh[reg], ul[reg]);
                }
                *(ushort4*)&dataH[((mt << 4) + l15) * LSTR + (w << 4) + (q << 2)] =
                    make_ushort4(uh[0], uh[1], uh[2], uh[3]);
                *(ushort4*)&dataLo[((mt << 4) + l15) * LSTR + (w << 4) + (q << 2)] =
                    make_ushort4(ul[0], ul[1], ul[2], ul[3]);
                csum += __shfl_xor(csum, 16);
                csum += __shfl_xor(csum, 32);
                if (q == 0) atomicAdd(&kcS[mg], csum);
            }
            __syncthreads();   // B2: uT complete

            // ctx MFMAs: D[m][e] += uT . v
            if (c < 4) {
                const int mrow = (w << 4) + l15;
                bfrag uH0 = *(const bfrag*)&dataH[mrow * LSTR + (q << 3)];
                bfrag uH1 = *(const bfrag*)&dataH[mrow * LSTR + 32 + (q << 3)];
                bfrag uL0 = *(const bfrag*)&dataLo[mrow * LSTR + (q << 3)];
                bfrag uL1 = *(const bfrag*)&dataLo[mrow * LSTR + 32 + (q << 3)];
                #pragma unroll
                for (int et = 0; et < 4; ++et) {
                    const int erow = (et << 4) + l15;
                    bfrag vH0 = *(const bfrag*)&vTH[swzV(erow, (q << 3))];
                    bfrag vH1 = *(const bfrag*)&vTH[swzV(erow, 32 + (q << 3))];
                    bfrag vL0 = *(const bfrag*)&vTLo[swzV(erow, (q << 3))];
                    bfrag vL1 = *(const bfrag*)&vTLo[swzV(erow, 32 + (q << 3))];
                    f32x4 a = cacc[c][et];
                    a = MFMA(uH0, vL0, a);
                    a = MFMA(uH1, vL1, a);
                    a = MFMA(uL0, vH0, a);
                    a = MFMA(uL1, vH1, a);
                    a = MFMA(uH0, vH0, a);
                    a = MFMA(uH1, vH1, a);
                    cacc[c][et] = a;
                }
            } else {
                const int mrow = l15;   // m-tile 16 uses rows 0..15 of uT buffer
                bfrag uH0 = *(const bfrag*)&dataH[mrow * LSTR + (q << 3)];
                bfrag uH1 = *(const bfrag*)&dataH[mrow * LSTR + 32 + (q << 3)];
                bfrag uL0 = *(const bfrag*)&dataLo[mrow * LSTR + (q << 3)];
                bfrag uL1 = *(const bfrag*)&dataLo[mrow * LSTR + 32 + (q << 3)];
                const int erow = (w << 4) + l15;   // wave w -> e-tile w
                bfrag vH0 = *(const bfrag*)&vTH[swzV(erow, (q << 3))];
                bfrag vH1 = *(const bfrag*)&vTH[swzV(erow, 32 + (q << 3))];
                bfrag vL0 = *(const bfrag*)&vTLo[swzV(erow, (q << 3))];
                bfrag vL1 = *(const bfrag*)&vTLo[swzV(erow, 32 + (q << 3))];
                f32x4 a = cacc4;
                a = MFMA(uH0, vL0, a);
                a = MFMA(uH1, vL1, a);
                a = MFMA(uL0, vH0, a);
                a = MFMA(uL1, vH1, a);
                a = MFMA(uH0, vH0, a);
                a = MFMA(uH1, vH1, a);
                cacc4 = a;
            }
        }
    }

    __syncthreads();
    // block dd-max + vsum LDS reduce
    {
        float bm = bmaxl;
        #pragma unroll
        for (int d = 1; d < 64; d <<= 1) bm = fmaxf(bm, __shfl_xor(bm, d));
        if (lane == 0) redS[w] = bm;
    }
    {
        const int e0 = (t << 2) & 63;
        atomicAdd(&vredS[e0 + 0], vacc.x);
        atomicAdd(&vredS[e0 + 1], vacc.y);
        atomicAdd(&vredS[e0 + 2], vacc.z);
        atomicAdd(&vredS[e0 + 3], vacc.w);
    }
    __syncthreads();
    if (t == 0) pmax[hd * 16 + nb] = fmaxf(fmaxf(redS[0], redS[1]), fmaxf(redS[2], redS[3]));
    if (t < DD) atomicAdd(&vsum[hd * DD + t], vredS[t]);
    // kc partial
    for (int m = t; m < MP; m += 256) kcP[(size_t)(hd * 16 + nb) * MP + m] = kcS[m];
    // ctx partial
    float* cp = ctxP + (size_t)(hd * 16 + nb) * MP * DD;
    #pragma unroll
    for (int c = 0; c < 4; ++c) {
        const int mbase = (c << 6) + (w << 4) + (q << 2);
        #pragma unroll
        for (int et = 0; et < 4; ++et)
            #pragma unroll
            for (int reg = 0; reg < 4; ++reg)
                cp[(mbase + reg) * DD + (et << 4) + l15] = cacc[c][et][reg];
    }
    #pragma unroll
    for (int reg = 0; reg < 4; ++reg)
        cp[(256 + (q << 2) + reg) * DD + (w << 4) + l15] = cacc4[reg];
}

// ===========================================================================
// ctx reduce: reduce the 512-entry pmax in-block (reduce_max kernel removed),
// sum 16 partials, scale by Asc=RATIO*e^-stab, add REPS*vsum, split to bf16,
// write TRANSPOSED gctxT[hd][e][m] (64 e-rows/head), and write the column-sum
// vector kcF as FLOAT.  grid (17 m-tiles, 32 heads)
// ===========================================================================
__global__ void ctx_reduce(const float* __restrict__ ctxP, const float* __restrict__ kcP,
                           const float* __restrict__ vsum, const float* __restrict__ pmax,
                           ushort* __restrict__ gH, ushort* __restrict__ gL,
                           float* __restrict__ kcF)
{
    __shared__ ushort hiT[64][20], loT[64][20];
    __shared__ float rmxS[4];
    const int t = threadIdx.x, mt = blockIdx.x, hd = blockIdx.y;
    const int lane = t & 63, w = t >> 6;
    // global stab = max over all 512 pmax entries
    float mxl = fmaxf(pmax[t], pmax[t + 256]);
    #pragma unroll
    for (int d = 1; d < 64; d <<= 1) mxl = fmaxf(mxl, __shfl_xor(mxl, d));
    if (lane == 0) rmxS[w] = mxl;
    __syncthreads();
    const float stab = fmaxf(fmaxf(rmxS[0], rmxS[1]), fmaxf(rmxS[2], rmxS[3]));
    const float Asc = RATIO * __expf(-stab);
    const float REPS = RATIO * EPSV;
    const int e = t & 63, mq = t >> 6;
    const float vs = vsum[hd * DD + e];
    #pragma unroll
    for (int i = 0; i < 4; ++i) {
        const int ml = mq * 4 + i;
        const int m = mt * 16 + ml;
        float s = 0.f;
        for (int nbk = 0; nbk < 16; ++nbk)
            s += ctxP[((size_t)(hd * 16 + nbk) * MP + m) * DD + e];
        float val = Asc * s + REPS * vs;
        ushort h, l; splitf(val, h, l);
        hiT[e][ml] = h; loT[e][ml] = l;
    }
    __syncthreads();
    {
        const int i = t * 4, e2 = i >> 4, cc = i & 15;
        ushort4 hv = make_ushort4(hiT[e2][cc], hiT[e2][cc + 1], hiT[e2][cc + 2], hiT[e2][cc + 3]);
        ushort4 lv = make_ushort4(loT[e2][cc], loT[e2][cc + 1], loT[e2][cc + 2], loT[e2][cc + 3]);
        *(ushort4*)(gH + ((size_t)hd * 64 + e2) * GSTR + mt * 16 + cc) = hv;
        *(ushort4*)(gL + ((size_t)hd * 64 + e2) * GSTR + mt * 16 + cc) = lv;
    }
    if (t < 16) {
        const int m = mt * 16 + t;
        float s = 0.f;
        for (int nbk = 0; nbk < 16; ++nbk) s += kcP[(size_t)(hd * 16 + nbk) * MP + m];
        kcF[hd * MP + m] = Asc * s + ((m < MM) ? REPS * (float)NN : 0.f);
    }
}

// ===========================================================================
// q-pass (round-2 v3, LSTR=72, unchanged): A-fragments + diag direct from
// global; phase 1: proj chunks LDS-staged, dd via MFMA; phase 2: rowmax +
// qp + VALU denominator; phase 3: qp scatter + ctxT chunks staged, out MFMAs.
// LDS 36.9 KB -> 4 blocks/CU.  grid (64 nblocks, 32 heads), block 256.
// ===========================================================================
__launch_bounds__(256, 4)
__global__ void qpass(const float* __restrict__ qin,
                      const ushort* __restrict__ pjH, const ushort* __restrict__ pjL,
                      const ushort* __restrict__ gH, const ushort* __restrict__ gL,
                      const float* __restrict__ kcF,
                      float* __restrict__ outp)
{
    __shared__ ushort bPH[64 * LSTR], bPL[64 * LSTR];   // proj chunk, then qpA
    __shared__ ushort bQH[64 * LSTR], bQL[64 * LSTR];   // ctxT chunk

    const int t = threadIdx.x;
    const int w = t >> 6;
    const int lane = t & 63;
    const int l15 = lane & 15;
    const int q = lane >> 4;
    const int hd = blockIdx.y;
    const int n0 = blockIdx.x << 6;

    // ---- A-fragments + diag, direct from global (once per block) ----
    const float* qb = qin + ((size_t)hd * NN + n0) * DD;
    const int row = (w << 4) + l15;
    float4 x0 = *(const float4*)(qb + (row << 6) + (q << 3));
    float4 x1 = *(const float4*)(qb + (row << 6) + (q << 3) + 4);
    float4 x2 = *(const float4*)(qb + (row << 6) + 32 + (q << 3));
    float4 x3 = *(const float4*)(qb + (row << 6) + 32 + (q << 3) + 4);
    x0.x *= NORMZ; x0.y *= NORMZ; x0.z *= NORMZ; x0.w *= NORMZ;
    x1.x *= NORMZ; x1.y *= NORMZ; x1.z *= NORMZ; x1.w *= NORMZ;
    x2.x *= NORMZ; x2.y *= NORMZ; x2.z *= NORMZ; x2.w *= NORMZ;
    x3.x *= NORMZ; x3.y *= NORMZ; x3.z *= NORMZ; x3.w *= NORMZ;
    float ss = x0.x*x0.x + x0.y*x0.y + x0.z*x0.z + x0.w*x0.w
             + x1.x*x1.x + x1.y*x1.y + x1.z*x1.z + x1.w*x1.w
             + x2.x*x2.x + x2.y*x2.y + x2.z*x2.z + x2.w*x2.w
             + x3.x*x3.x + x3.y*x3.y + x3.z*x3.z + x3.w*x3.w;
    ss += __shfl_xor(ss, 16);
    ss += __shfl_xor(ss, 32);
    float dg[4];
    #pragma unroll
    for (int r = 0; r < 4; ++r) dg[r] = 0.5f * __shfl(ss, (q << 2) + r);
    bfrag aH[2], aL[2];
    pack8(x0, x1, aH[0], aL[0]);
    pack8(x2, x3, aH[1], aL[1]);

    const f32x4 zf = {0.f, 0.f, 0.f, 0.f};
    f32x4 ddq[17];

    // ---- phase 1: dd for all 272 m (proj chunks via LDS) ----
    #pragma unroll
    for (int c = 0; c < 5; ++c) {
        const int mtiles = (c < 4) ? 4 : 1;
        const int m0 = c << 6;
        __syncthreads();   // prior chunk's fragment readers done
        {
            const int tot = mtiles << 7;
            for (int idx = t; idx < tot; idx += 256) {
                int i = idx << 3; int r = i >> 6, cc = i & 63;
                *(uint4*)&bPH[r * LSTR + cc] = *(const uint4*)(pjH + ((m0 + r) << 6) + cc);
                *(uint4*)&bPL[r * LSTR + cc] = *(const uint4*)(pjL + ((m0 + r) << 6) + cc);
            }
        }
        __syncthreads();
        #pragma unroll
        for (int mt = 0; mt < 4; ++mt) {
            if (mt >= mtiles) break;
            const int mrow = (mt << 4) + l15;
            bfrag bH0 = *(const bfrag*)&bPH[mrow * LSTR + (q << 3)];
            bfrag bH1 = *(const bfrag*)&bPH[mrow * LSTR + 32 + (q << 3)];
            bfrag bL0 = *(const bfrag*)&bPL[mrow * LSTR + (q << 3)];
            bfrag bL1 = *(const bfrag*)&bPL[mrow * LSTR + 32 + (q << 3)];
            f32x4 a = zf;
            a = MFMA(aH[0], bL0, a);
            a = MFMA(aH[1], bL1, a);
            a = MFMA(aL[0], bH0, a);
            a = MFMA(aL[1], bH1, a);
            a = MFMA(aH[0], bH0, a);
            a = MFMA(aH[1], bH1, a);
            ddq[c * 4 + mt] = a;
        }
    }

    // ---- phase 2: rowmax + qp + denominator (registers only) ----
    float rmax[4];
    #pragma unroll
    for (int reg = 0; reg < 4; ++reg) {
        float mx = NEG_INF;
        #pragma unroll
        for (int ti = 0; ti < 17; ++ti) {
            bool valid = (ti < 16) || (l15 < 10);
            if (valid) mx = fmaxf(mx, ddq[ti][reg]);
        }
        #pragma unroll
        for (int d = 1; d < 16; d <<= 1) mx = fmaxf(mx, __shfl_xor(mx, d));
        rmax[reg] = mx;
    }
    #pragma unroll
    for (int ti = 0; ti < 17; ++ti) {
        #pragma unroll
        for (int reg = 0; reg < 4; ++reg) {
            bool valid = (ti < 16) || (l15 < 10);
            float e = 0.f;
            if (valid)
                e = RATIO * (__expf(ddq[ti][reg] - dg[reg] - rmax[reg]) + EPSV);
            ddq[ti][reg] = e;
        }
    }
    // denominator: den[n] = sum_m qp[n][m]*kc[m], lands in the owning lanes
    float dinv[4];
    {
        const float* kcb = kcF + hd * MP;
        float den[4] = {0.f, 0.f, 0.f, 0.f};
        #pragma unroll
        for (int ti = 0; ti < 17; ++ti) {
            float kv = kcb[(ti << 4) + l15];
            #pragma unroll
            for (int reg = 0; reg < 4; ++reg) den[reg] += ddq[ti][reg] * kv;
        }
        #pragma unroll
        for (int reg = 0; reg < 4; ++reg) {
            #pragma unroll
            for (int d = 1; d < 16; d <<= 1) den[reg] += __shfl_xor(den[reg], d);
            dinv[reg] = 1.f / den[reg];
        }
    }

    // ---- phase 3: out = qp @ ctxT (qp chunk in bufP, ctxT chunk in bufQ) ----
    f32x4 oacc[4];
    #pragma unroll
    for (int et = 0; et < 4; ++et) oacc[et] = zf;

    #pragma unroll
    for (int c = 0; c < 5; ++c) {
        const int mtiles = (c < 4) ? 4 : 1;
        __syncthreads();   // prior chunk's bufP/bufQ readers done
        // scatter qp chunk (own rows only)
        #pragma unroll
        for (int mt = 0; mt < 4; ++mt) {
            if (mt >= mtiles) break;
            const int ml = (mt << 4) + l15;
            #pragma unroll
            for (int reg = 0; reg < 4; ++reg) {
                ushort hh, ll; splitf(ddq[c * 4 + mt][reg], hh, ll);
                bPH[((w << 4) + (q << 2) + reg) * LSTR + ml] = hh;
                bPL[((w << 4) + (q << 2) + reg) * LSTR + ml] = ll;
            }
        }
        if (c == 4) {   // zero-pad qp cols 16..31 (K-step padding)
            const int rown = (w << 4) + l15;
            *(ushort4*)&bPH[rown * LSTR + 16 + (q << 2)] = make_ushort4(0, 0, 0, 0);
            *(ushort4*)&bPL[rown * LSTR + 16 + (q << 2)] = make_ushort4(0, 0, 0, 0);
        }
        // stage ctxT chunk [64 e][64 m] (coalesced)
        {
            for (int idx = t; idx < 512; idx += 256) {
                int i = idx << 3; int e = i >> 6, mm = i & 63;
                *(uint4*)&bQH[e * LSTR + mm] =
                    *(const uint4*)(gH + ((size_t)hd * 64 + e) * GSTR + (c << 6) + mm);
                *(uint4*)&bQL[e * LSTR + mm] =
                    *(const uint4*)(gL + ((size_t)hd * 64 + e) * GSTR + (c << 6) + mm);
            }
        }
        __syncthreads();
        const int arow = (w << 4) + l15;
        bfrag pH0 = *(const bfrag*)&bPH[arow * LSTR + (q << 3)];
        bfrag pL0 = *(const bfrag*)&bPL[arow * LSTR + (q << 3)];
        bfrag pH1, pL1;
        if (c < 4) {
            pH1 = *(const bfrag*)&bPH[arow * LSTR + 32 + (q << 3)];
            pL1 = *(const bfrag*)&bPL[arow * LSTR + 32 + (q << 3)];
        }
        #pragma unroll
        for (int et = 0; et < 4; ++et) {
            const int erow = (et << 4) + l15;
            bfrag cH0 = *(const bfrag*)&bQH[erow * LSTR + (q << 3)];
            bfrag cL0 = *(const bfrag*)&bQL[erow * LSTR + (q << 3)];
            f32x4 a = oacc[et];
            a = MFMA(pH0, cL0, a);
            a = MFMA(pL0, cH0, a);
            a = MFMA(pH0, cH0, a);
            if (c < 4) {
                bfrag cH1 = *(const bfrag*)&bQH[erow * LSTR + 32 + (q << 3)];
                bfrag cL1 = *(const bfrag*)&bQL[erow * LSTR + 32 + (q << 3)];
                a = MFMA(pH1, cL1, a);
                a = MFMA(pL1, cH1, a);
                a = MFMA(pH1, cH1, a);
            }
            oacc[et] = a;
        }
    }

    // ---- epilogue: scale by 1/den (already in the owning lanes) ----
    float* ob = outp + ((size_t)hd * NN + n0) * DD;
    #pragma unroll
    for (int et = 0; et < 4; ++et)
        #pragma unroll
        for (int reg = 0; reg < 4; ++reg)
            ob[((w << 4) + (q << 2) + reg) * DD + (et << 4) + l15] = oacc[et][reg] * dinv[reg];
}

// ---------------------------------------------------------------------------
extern "C" void kernel_launch(void* const* d_in, const int* in_sizes, int n_in,
                              void* d_out, int out_size, void* d_ws, size_t ws_size,
                              hipStream_t stream)
{
    const float* q = (const float*)d_in[0];
    const float* k = (const float*)d_in[1];
    const float* v = (const float*)d_in[2];
    const float* proj = (const float*)d_in[3];
    float* out = (float*)d_out;
    char* ws = (char*)d_ws;

    ushort* gH  = (ushort*)(ws);                    // 32*64*320*2 = 1,310,720 B
    ushort* gL  = (ushort*)(ws + 1310720);          // 1,310,720 B
    float*  vsm = (float*)(ws + 2621440);           // 8,192 B
    ushort* pH  = (ushort*)(ws + 2629632);          // 34,816 B
    ushort* pL  = (ushort*)(ws + 2664448);          // 34,816 B
    float*  kcF = (float*)(ws + 2699264);           // 34,816 B
    float*  ctxP= (float*)(ws + 2734080);           // 512*272*64*4 = 35,651,584 B
    float*  kcP = (float*)(ws + 38385664);          // 557,056 B
    float*  pmax= (float*)(ws + 38942720);          // 2,048 B

    hipMemsetAsync(ws, 0, 2629632, stream);         // gH, gL, vsum

    proj_split<<<dim3(17), 256, 0, stream>>>(proj, pH, pL);
    kpass<<<dim3(16, 32), 256, 0, stream>>>(k, v, pH, pL, ctxP, kcP, pmax, vsm);
    ctx_reduce<<<dim3(17, 32), 256, 0, stream>>>(ctxP, kcP, vsm, pmax, gH, gL, kcF);
    qpass<<<dim3(64, 32), 256, 0, stream>>>(q, pH, pL, gH, gL, kcF, out);
}

// Round 7
// 242.835 us; speedup vs baseline: 1.1486x; 1.0527x over previous
//
#include <hip/hip_runtime.h>
#include <math.h>

#define NN 4096
#define DD 64
#define MM 266
#define MP 272
#define NORMZ 0.35355339059327379f   // 64^-0.25
#define RATIO 0.06131393394849658f   // 266^-0.5
#define EPSV 1e-4f
#define NEG_INF (-3.4e38f)
#define LSTR 72                       // LDS row stride in ushorts (144B, 16B aligned)
#define GSTR 320                      // gctxT row stride in ushorts

typedef __attribute__((ext_vector_type(8))) short bfrag;
typedef __attribute__((ext_vector_type(4))) float f32x4;

#define MFMA(a, b, c) __builtin_amdgcn_mfma_f32_16x16x32_bf16((a), (b), (c), 0, 0, 0)

__device__ inline ushort bf16rne(float x) {
    union { float f; unsigned u; } c; c.f = x;
    unsigned r = c.u + 0x7FFFu + ((c.u >> 16) & 1u);
    return (ushort)(r >> 16);
}
__device__ inline float bf2f(ushort h) {
    union { unsigned u; float f; } c; c.u = ((unsigned)h) << 16;
    return c.f;
}
__device__ inline void splitf(float x, ushort& h, ushort& l) {
    h = bf16rne(x);
    l = bf16rne(x - bf2f(h));
}
// pack 8 scaled floats (two float4) into split bf16 fragments
__device__ inline void pack8(const float4& a, const float4& b, bfrag& H, bfrag& L) {
    ushort h, l;
    splitf(a.x, h, l); H[0] = (short)h; L[0] = (short)l;
    splitf(a.y, h, l); H[1] = (short)h; L[1] = (short)l;
    splitf(a.z, h, l); H[2] = (short)h; L[2] = (short)l;
    splitf(a.w, h, l); H[3] = (short)h; L[3] = (short)l;
    splitf(b.x, h, l); H[4] = (short)h; L[4] = (short)l;
    splitf(b.y, h, l); H[5] = (short)h; L[5] = (short)l;
    splitf(b.z, h, l); H[6] = (short)h; L[6] = (short)l;
    splitf(b.w, h, l); H[7] = (short)h; L[7] = (short)l;
}

// ---------------------------------------------------------------------------
// proj split: proj fp32 [266][64] -> pH/pL bf16 [272][64] (rows >=266 zero)
// ---------------------------------------------------------------------------
__global__ void proj_split(const float* __restrict__ proj,
                           ushort* __restrict__ pH, ushort* __restrict__ pL)
{
    int i = (blockIdx.x * 256 + threadIdx.x) * 4;   // 17*256*4 = 17408 = 272*64
    int m = i >> 6;
    float4 x = (m < MM) ? *(const float4*)(proj + i) : make_float4(0.f, 0.f, 0.f, 0.f);
    ushort h0, l0, h1, l1, h2, l2, h3, l3;
    splitf(x.x, h0, l0); splitf(x.y, h1, l1); splitf(x.z, h2, l2); splitf(x.w, h3, l3);
    *(ushort4*)(pH + i) = make_ushort4(h0, h1, h2, h3);
    *(ushort4*)(pL + i) = make_ushort4(l0, l1, l2, l3);
}

// ===========================================================================
// k-pass v7: round-2 structure (256 threads, 4 waves, 2 blocks/CU, LSTR=72
// plain everywhere — no swizzle, it cost more in codegen than it saved in
// banks) with ONE change: the dataA LDS staging is gone.  A-fragments load
// 16B-contiguous direct from global k (qpass-proven pattern); diag via 3
// shfls.  dataH/dataLo now serve only as the uT buffer.
// Per 64-row subtile: dd = (NORMZ*k)@proj^T via split-bf16 MFMA,
// u = exp(dd - diag), block dd-max, ctx partial += uT@v via MFMA,
// kc partial += colsum(u).  vsum fused.  grid (16 nblocks, 32 heads).
// ===========================================================================
__launch_bounds__(256, 2)
__global__ void kpass(const float* __restrict__ kin, const float* __restrict__ vin,
                      const ushort* __restrict__ pjH, const ushort* __restrict__ pjL,
                      float* __restrict__ ctxP, float* __restrict__ kcP,
                      float* __restrict__ pmax, float* __restrict__ vsum)
{
    __shared__ ushort dataH[64 * LSTR], dataLo[64 * LSTR];  // uT buffer
    __shared__ ushort vTH[64 * LSTR], vTLo[64 * LSTR];      // [e][n]
    __shared__ ushort r2H[64 * LSTR], r2Lo[64 * LSTR];      // projL chunk [m_l][k]
    __shared__ float kcS[MP];
    __shared__ float redS[4];
    __shared__ float vredS[DD];

    const int t = threadIdx.x;
    const int w = t >> 6;
    const int lane = t & 63;
    const int l15 = lane & 15;
    const int q = lane >> 4;
    const int hd = blockIdx.y;
    const int nb = blockIdx.x;

    kcS[t] = 0.f;
    if (t < 16) kcS[256 + t] = 0.f;
    if (t < DD) vredS[t] = 0.f;

    const f32x4 zf = {0.f, 0.f, 0.f, 0.f};
    f32x4 cacc[4][4];
    f32x4 cacc4 = zf;
    #pragma unroll
    for (int c = 0; c < 4; ++c)
        #pragma unroll
        for (int e = 0; e < 4; ++e) cacc[c][e] = zf;
    float bmaxl = NEG_INF;
    float4 vacc = make_float4(0.f, 0.f, 0.f, 0.f);

    #pragma unroll 1
    for (int st = 0; st < 4; ++st) {
        const int n0 = (nb << 8) + (st << 6);
        __syncthreads();   // protect vT/uT restage vs last chunk's ctx readers

        // ---- stage vT (split, transposed) + vsum accumulate ----
        const float* vb = vin + ((size_t)hd * NN + n0) * DD;
        #pragma unroll
        for (int j = 0; j < 4; ++j) {
            int i = (t + (j << 8)) << 2;
            int n = i >> 6, e = i & 63;
            float4 x = *(const float4*)(vb + i);
            vacc.x += x.x; vacc.y += x.y; vacc.z += x.z; vacc.w += x.w;
            ushort h, l;
            splitf(x.x, h, l); vTH[(e + 0) * LSTR + n] = h; vTLo[(e + 0) * LSTR + n] = l;
            splitf(x.y, h, l); vTH[(e + 1) * LSTR + n] = h; vTLo[(e + 1) * LSTR + n] = l;
            splitf(x.z, h, l); vTH[(e + 2) * LSTR + n] = h; vTLo[(e + 2) * LSTR + n] = l;
            splitf(x.w, h, l); vTH[(e + 3) * LSTR + n] = h; vTLo[(e + 3) * LSTR + n] = l;
        }

        // ---- A-fragments + diag, direct from global (no LDS round trip) ----
        const float* kb = kin + ((size_t)hd * NN + n0) * DD;
        const int row = (w << 4) + l15;
        float4 x0 = *(const float4*)(kb + (row << 6) + (q << 3));
        float4 x1 = *(const float4*)(kb + (row << 6) + (q << 3) + 4);
        float4 x2 = *(const float4*)(kb + (row << 6) + 32 + (q << 3));
        float4 x3 = *(const float4*)(kb + (row << 6) + 32 + (q << 3) + 4);
        x0.x *= NORMZ; x0.y *= NORMZ; x0.z *= NORMZ; x0.w *= NORMZ;
        x1.x *= NORMZ; x1.y *= NORMZ; x1.z *= NORMZ; x1.w *= NORMZ;
        x2.x *= NORMZ; x2.y *= NORMZ; x2.z *= NORMZ; x2.w *= NORMZ;
        x3.x *= NORMZ; x3.y *= NORMZ; x3.z *= NORMZ; x3.w *= NORMZ;
        float ss = x0.x*x0.x + x0.y*x0.y + x0.z*x0.z + x0.w*x0.w
                 + x1.x*x1.x + x1.y*x1.y + x1.z*x1.z + x1.w*x1.w
                 + x2.x*x2.x + x2.y*x2.y + x2.z*x2.z + x2.w*x2.w
                 + x3.x*x3.x + x3.y*x3.y + x3.z*x3.z + x3.w*x3.w;
        ss += __shfl_xor(ss, 16);
        ss += __shfl_xor(ss, 32);
        float dg[4];
        #pragma unroll
        for (int r = 0; r < 4; ++r) dg[r] = 0.5f * __shfl(ss, (q << 2) + r);
        bfrag aH[2], aL[2];
        pack8(x0, x1, aH[0], aL[0]);
        pack8(x2, x3, aH[1], aL[1]);
        __syncthreads();   // vT ready

        #pragma unroll
        for (int c = 0; c < 5; ++c) {
            const int mtiles = (c < 4) ? 4 : 1;
            const int m0 = c << 6;
            // stage projL chunk (r2)
            {
                const int tot = mtiles << 7;   // mtiles*16*64/8
                for (int idx = t; idx < tot; idx += 256) {
                    int i = idx << 3; int r = i >> 6, cc = i & 63;
                    *(uint4*)&r2H[r * LSTR + cc] = *(const uint4*)(pjH + ((m0 + r) << 6) + cc);
                    *(uint4*)&r2Lo[r * LSTR + cc] = *(const uint4*)(pjL + ((m0 + r) << 6) + cc);
                }
            }
            __syncthreads();   // B1: projL ready; prior ctx readers of uT done

            // dd MFMAs
            f32x4 dd4[4];
            #pragma unroll
            for (int mt = 0; mt < 4; ++mt) {
                if (mt >= mtiles) break;
                const int mrow = (mt << 4) + l15;
                bfrag bH0 = *(const bfrag*)&r2H[mrow * LSTR + (q << 3)];
                bfrag bH1 = *(const bfrag*)&r2H[mrow * LSTR + 32 + (q << 3)];
                bfrag bL0 = *(const bfrag*)&r2Lo[mrow * LSTR + (q << 3)];
                bfrag bL1 = *(const bfrag*)&r2Lo[mrow * LSTR + 32 + (q << 3)];
                f32x4 a = zf;
                a = MFMA(aH[0], bL0, a);
                a = MFMA(aH[1], bL1, a);
                a = MFMA(aL[0], bH0, a);
                a = MFMA(aL[1], bH1, a);
                a = MFMA(aH[0], bH0, a);
                a = MFMA(aH[1], bH1, a);
                dd4[mt] = a;
            }
            // exp + max + kc + scatter uT into data region
            #pragma unroll
            for (int mt = 0; mt < 4; ++mt) {
                if (mt >= mtiles) break;
                const int mg = m0 + (mt << 4) + l15;
                const bool valid = (mg < MM);
                ushort uh[4], ul[4];
                float csum = 0.f;
                #pragma unroll
                for (int reg = 0; reg < 4; ++reg) {
                    float dv = dd4[mt][reg];
                    float u = 0.f;
                    if (valid) {
                        bmaxl = fmaxf(bmaxl, dv);
                        u = __expf(dv - dg[reg]);
                    }
                    csum += u;
                    splitf(u, uh[reg], ul[reg]);
                }
                *(ushort4*)&dataH[((mt << 4) + l15) * LSTR + (w << 4) + (q << 2)] =
                    make_ushort4(uh[0], uh[1], uh[2], uh[3]);
                *(ushort4*)&dataLo[((mt << 4) + l15) * LSTR + (w << 4) + (q << 2)] =
                    make_ushort4(ul[0], ul[1], ul[2], ul[3]);
                csum += __shfl_xor(csum, 16);
                csum += __shfl_xor(csum, 32);
                if (q == 0) atomicAdd(&kcS[mg], csum);
            }
            __syncthreads();   // B2: uT complete

            // ctx MFMAs: D[m][e] += uT . v
            if (c < 4) {
                const int mrow = (w << 4) + l15;
                bfrag uH0 = *(const bfrag*)&dataH[mrow * LSTR + (q << 3)];
                bfrag uH1 = *(const bfrag*)&dataH[mrow * LSTR + 32 + (q << 3)];
                bfrag uL0 = *(const bfrag*)&dataLo[mrow * LSTR + (q << 3)];
                bfrag uL1 = *(const bfrag*)&dataLo[mrow * LSTR + 32 + (q << 3)];
                #pragma unroll
                for (int et = 0; et < 4; ++et) {
                    const int erow = (et << 4) + l15;
                    bfrag vH0 = *(const bfrag*)&vTH[erow * LSTR + (q << 3)];
                    bfrag vH1 = *(const bfrag*)&vTH[erow * LSTR + 32 + (q << 3)];
                    bfrag vL0 = *(const bfrag*)&vTLo[erow * LSTR + (q << 3)];
                    bfrag vL1 = *(const bfrag*)&vTLo[erow * LSTR + 32 + (q << 3)];
                    f32x4 a = cacc[c][et];
                    a = MFMA(uH0, vL0, a);
                    a = MFMA(uH1, vL1, a);
                    a = MFMA(uL0, vH0, a);
                    a = MFMA(uL1, vH1, a);
                    a = MFMA(uH0, vH0, a);
                    a = MFMA(uH1, vH1, a);
                    cacc[c][et] = a;
                }
            } else {
                const int mrow = l15;   // m-tile 16 uses rows 0..15 of uT buffer
                bfrag uH0 = *(const bfrag*)&dataH[mrow * LSTR + (q << 3)];
                bfrag uH1 = *(const bfrag*)&dataH[mrow * LSTR + 32 + (q << 3)];
                bfrag uL0 = *(const bfrag*)&dataLo[mrow * LSTR + (q << 3)];
                bfrag uL1 = *(const bfrag*)&dataLo[mrow * LSTR + 32 + (q << 3)];
                const int erow = (w << 4) + l15;   // wave w -> e-tile w
                bfrag vH0 = *(const bfrag*)&vTH[erow * LSTR + (q << 3)];
                bfrag vH1 = *(const bfrag*)&vTH[erow * LSTR + 32 + (q << 3)];
                bfrag vL0 = *(const bfrag*)&vTLo[erow * LSTR + (q << 3)];
                bfrag vL1 = *(const bfrag*)&vTLo[erow * LSTR + 32 + (q << 3)];
                f32x4 a = cacc4;
                a = MFMA(uH0, vL0, a);
                a = MFMA(uH1, vL1, a);
                a = MFMA(uL0, vH0, a);
                a = MFMA(uL1, vH1, a);
                a = MFMA(uH0, vH0, a);
                a = MFMA(uH1, vH1, a);
                cacc4 = a;
            }
        }
    }

    __syncthreads();
    // block dd-max + vsum LDS reduce
    {
        float bm = bmaxl;
        #pragma unroll
        for (int d = 1; d < 64; d <<= 1) bm = fmaxf(bm, __shfl_xor(bm, d));
        if (lane == 0) redS[w] = bm;
    }
    {
        const int e0 = (t << 2) & 63;
        atomicAdd(&vredS[e0 + 0], vacc.x);
        atomicAdd(&vredS[e0 + 1], vacc.y);
        atomicAdd(&vredS[e0 + 2], vacc.z);
        atomicAdd(&vredS[e0 + 3], vacc.w);
    }
    __syncthreads();
    if (t == 0) pmax[hd * 16 + nb] = fmaxf(fmaxf(redS[0], redS[1]), fmaxf(redS[2], redS[3]));
    if (t < DD) atomicAdd(&vsum[hd * DD + t], vredS[t]);
    // kc partial
    for (int m = t; m < MP; m += 256) kcP[(size_t)(hd * 16 + nb) * MP + m] = kcS[m];
    // ctx partial
    float* cp = ctxP + (size_t)(hd * 16 + nb) * MP * DD;
    #pragma unroll
    for (int c = 0; c < 4; ++c) {
        const int mbase = (c << 6) + (w << 4) + (q << 2);
        #pragma unroll
        for (int et = 0; et < 4; ++et)
            #pragma unroll
            for (int reg = 0; reg < 4; ++reg)
                cp[(mbase + reg) * DD + (et << 4) + l15] = cacc[c][et][reg];
    }
    #pragma unroll
    for (int reg = 0; reg < 4; ++reg)
        cp[(256 + (q << 2) + reg) * DD + (w << 4) + l15] = cacc4[reg];
}

// ===========================================================================
// ctx reduce: reduce the 512-entry pmax in-block, sum 16 partials, scale by
// Asc=RATIO*e^-stab, add REPS*vsum, split to bf16, write TRANSPOSED
// gctxT[hd][e][m] (64 e-rows/head), and write kcF as FLOAT.
// grid (17 m-tiles, 32 heads)
// ===========================================================================
__global__ void ctx_reduce(const float* __restrict__ ctxP, const float* __restrict__ kcP,
                           const float* __restrict__ vsum, const float* __restrict__ pmax,
                           ushort* __restrict__ gH, ushort* __restrict__ gL,
                           float* __restrict__ kcF)
{
    __shared__ ushort hiT[64][20], loT[64][20];
    __shared__ float rmxS[4];
    const int t = threadIdx.x, mt = blockIdx.x, hd = blockIdx.y;
    const int lane = t & 63, w = t >> 6;
    float mxl = fmaxf(pmax[t], pmax[t + 256]);
    #pragma unroll
    for (int d = 1; d < 64; d <<= 1) mxl = fmaxf(mxl, __shfl_xor(mxl, d));
    if (lane == 0) rmxS[w] = mxl;
    __syncthreads();
    const float stab = fmaxf(fmaxf(rmxS[0], rmxS[1]), fmaxf(rmxS[2], rmxS[3]));
    const float Asc = RATIO * __expf(-stab);
    const float REPS = RATIO * EPSV;
    const int e = t & 63, mq = t >> 6;
    const float vs = vsum[hd * DD + e];
    #pragma unroll
    for (int i = 0; i < 4; ++i) {
        const int ml = mq * 4 + i;
        const int m = mt * 16 + ml;
        float s = 0.f;
        for (int nbk = 0; nbk < 16; ++nbk)
            s += ctxP[((size_t)(hd * 16 + nbk) * MP + m) * DD + e];
        float val = Asc * s + REPS * vs;
        ushort h, l; splitf(val, h, l);
        hiT[e][ml] = h; loT[e][ml] = l;
    }
    __syncthreads();
    {
        const int i = t * 4, e2 = i >> 4, cc = i & 15;
        ushort4 hv = make_ushort4(hiT[e2][cc], hiT[e2][cc + 1], hiT[e2][cc + 2], hiT[e2][cc + 3]);
        ushort4 lv = make_ushort4(loT[e2][cc], loT[e2][cc + 1], loT[e2][cc + 2], loT[e2][cc + 3]);
        *(ushort4*)(gH + ((size_t)hd * 64 + e2) * GSTR + mt * 16 + cc) = hv;
        *(ushort4*)(gL + ((size_t)hd * 64 + e2) * GSTR + mt * 16 + cc) = lv;
    }
    if (t < 16) {
        const int m = mt * 16 + t;
        float s = 0.f;
        for (int nbk = 0; nbk < 16; ++nbk) s += kcP[(size_t)(hd * 16 + nbk) * MP + m];
        kcF[hd * MP + m] = Asc * s + ((m < MM) ? REPS * (float)NN : 0.f);
    }
}

// ===========================================================================
// q-pass (round-2 v3, unchanged): A-fragments + diag direct from global;
// phase 1: proj chunks LDS-staged, dd via MFMA; phase 2: rowmax + qp + VALU
// denominator; phase 3: qp scatter + ctxT chunks staged, out MFMAs.
// LDS 36.9 KB -> 4 blocks/CU.  grid (64 nblocks, 32 heads), block 256.
// ===========================================================================
__launch_bounds__(256, 4)
__global__ void qpass(const float* __restrict__ qin,
                      const ushort* __restrict__ pjH, const ushort* __restrict__ pjL,
                      const ushort* __restrict__ gH, const ushort* __restrict__ gL,
                      const float* __restrict__ kcF,
                      float* __restrict__ outp)
{
    __shared__ ushort bPH[64 * LSTR], bPL[64 * LSTR];   // proj chunk, then qpA
    __shared__ ushort bQH[64 * LSTR], bQL[64 * LSTR];   // ctxT chunk

    const int t = threadIdx.x;
    const int w = t >> 6;
    const int lane = t & 63;
    const int l15 = lane & 15;
    const int q = lane >> 4;
    const int hd = blockIdx.y;
    const int n0 = blockIdx.x << 6;

    const float* qb = qin + ((size_t)hd * NN + n0) * DD;
    const int row = (w << 4) + l15;
    float4 x0 = *(const float4*)(qb + (row << 6) + (q << 3));
    float4 x1 = *(const float4*)(qb + (row << 6) + (q << 3) + 4);
    float4 x2 = *(const float4*)(qb + (row << 6) + 32 + (q << 3));
    float4 x3 = *(const float4*)(qb + (row << 6) + 32 + (q << 3) + 4);
    x0.x *= NORMZ; x0.y *= NORMZ; x0.z *= NORMZ; x0.w *= NORMZ;
    x1.x *= NORMZ; x1.y *= NORMZ; x1.z *= NORMZ; x1.w *= NORMZ;
    x2.x *= NORMZ; x2.y *= NORMZ; x2.z *= NORMZ; x2.w *= NORMZ;
    x3.x *= NORMZ; x3.y *= NORMZ; x3.z *= NORMZ; x3.w *= NORMZ;
    float ss = x0.x*x0.x + x0.y*x0.y + x0.z*x0.z + x0.w*x0.w
             + x1.x*x1.x + x1.y*x1.y + x1.z*x1.z + x1.w*x1.w
             + x2.x*x2.x + x2.y*x2.y + x2.z*x2.z + x2.w*x2.w
             + x3.x*x3.x + x3.y*x3.y + x3.z*x3.z + x3.w*x3.w;
    ss += __shfl_xor(ss, 16);
    ss += __shfl_xor(ss, 32);
    float dg[4];
    #pragma unroll
    for (int r = 0; r < 4; ++r) dg[r] = 0.5f * __shfl(ss, (q << 2) + r);
    bfrag aH[2], aL[2];
    pack8(x0, x1, aH[0], aL[0]);
    pack8(x2, x3, aH[1], aL[1]);

    const f32x4 zf = {0.f, 0.f, 0.f, 0.f};
    f32x4 ddq[17];

    // ---- phase 1: dd for all 272 m (proj chunks via LDS) ----
    #pragma unroll
    for (int c = 0; c < 5; ++c) {
        const int mtiles = (c < 4) ? 4 : 1;
        const int m0 = c << 6;
        __syncthreads();
        {
            const int tot = mtiles << 7;
            for (int idx = t; idx < tot; idx += 256) {
                int i = idx << 3; int r = i >> 6, cc = i & 63;
                *(uint4*)&bPH[r * LSTR + cc] = *(const uint4*)(pjH + ((m0 + r) << 6) + cc);
                *(uint4*)&bPL[r * LSTR + cc] = *(const uint4*)(pjL + ((m0 + r) << 6) + cc);
            }
        }
        __syncthreads();
        #pragma unroll
        for (int mt = 0; mt < 4; ++mt) {
            if (mt >= mtiles) break;
            const int mrow = (mt << 4) + l15;
            bfrag bH0 = *(const bfrag*)&bPH[mrow * LSTR + (q << 3)];
            bfrag bH1 = *(const bfrag*)&bPH[mrow * LSTR + 32 + (q << 3)];
            bfrag bL0 = *(const bfrag*)&bPL[mrow * LSTR + (q << 3)];
            bfrag bL1 = *(const bfrag*)&bPL[mrow * LSTR + 32 + (q << 3)];
            f32x4 a = zf;
            a = MFMA(aH[0], bL0, a);
            a = MFMA(aH[1], bL1, a);
            a = MFMA(aL[0], bH0, a);
            a = MFMA(aL[1], bH1, a);
            a = MFMA(aH[0], bH0, a);
            a = MFMA(aH[1], bH1, a);
            ddq[c * 4 + mt] = a;
        }
    }

    // ---- phase 2: rowmax + qp + denominator (registers only) ----
    float rmax[4];
    #pragma unroll
    for (int reg = 0; reg < 4; ++reg) {
        float mx = NEG_INF;
        #pragma unroll
        for (int ti = 0; ti < 17; ++ti) {
            bool valid = (ti < 16) || (l15 < 10);
            if (valid) mx = fmaxf(mx, ddq[ti][reg]);
        }
        #pragma unroll
        for (int d = 1; d < 16; d <<= 1) mx = fmaxf(mx, __shfl_xor(mx, d));
        rmax[reg] = mx;
    }
    #pragma unroll
    for (int ti = 0; ti < 17; ++ti) {
        #pragma unroll
        for (int reg = 0; reg < 4; ++reg) {
            bool valid = (ti < 16) || (l15 < 10);
            float e = 0.f;
            if (valid)
                e = RATIO * (__expf(ddq[ti][reg] - dg[reg] - rmax[reg]) + EPSV);
            ddq[ti][reg] = e;
        }
    }
    float dinv[4];
    {
        const float* kcb = kcF + hd * MP;
        float den[4] = {0.f, 0.f, 0.f, 0.f};
        #pragma unroll
        for (int ti = 0; ti < 17; ++ti) {
            float kv = kcb[(ti << 4) + l15];
            #pragma unroll
            for (int reg = 0; reg < 4; ++reg) den[reg] += ddq[ti][reg] * kv;
        }
        #pragma unroll
        for (int reg = 0; reg < 4; ++reg) {
            #pragma unroll
            for (int d = 1; d < 16; d <<= 1) den[reg] += __shfl_xor(den[reg], d);
            dinv[reg] = 1.f / den[reg];
        }
    }

    // ---- phase 3: out = qp @ ctxT (qp chunk in bufP, ctxT chunk in bufQ) ----
    f32x4 oacc[4];
    #pragma unroll
    for (int et = 0; et < 4; ++et) oacc[et] = zf;

    #pragma unroll
    for (int c = 0; c < 5; ++c) {
        const int mtiles = (c < 4) ? 4 : 1;
        __syncthreads();
        #pragma unroll
        for (int mt = 0; mt < 4; ++mt) {
            if (mt >= mtiles) break;
            const int ml = (mt << 4) + l15;
            #pragma unroll
            for (int reg = 0; reg < 4; ++reg) {
                ushort hh, ll; splitf(ddq[c * 4 + mt][reg], hh, ll);
                bPH[((w << 4) + (q << 2) + reg) * LSTR + ml] = hh;
                bPL[((w << 4) + (q << 2) + reg) * LSTR + ml] = ll;
            }
        }
        if (c == 4) {
            const int rown = (w << 4) + l15;
            *(ushort4*)&bPH[rown * LSTR + 16 + (q << 2)] = make_ushort4(0, 0, 0, 0);
            *(ushort4*)&bPL[rown * LSTR + 16 + (q << 2)] = make_ushort4(0, 0, 0, 0);
        }
        {
            for (int idx = t; idx < 512; idx += 256) {
                int i = idx << 3; int e = i >> 6, mm = i & 63;
                *(uint4*)&bQH[e * LSTR + mm] =
                    *(const uint4*)(gH + ((size_t)hd * 64 + e) * GSTR + (c << 6) + mm);
                *(uint4*)&bQL[e * LSTR + mm] =
                    *(const uint4*)(gL + ((size_t)hd * 64 + e) * GSTR + (c << 6) + mm);
            }
        }
        __syncthreads();
        const int arow = (w << 4) + l15;
        bfrag pH0 = *(const bfrag*)&bPH[arow * LSTR + (q << 3)];
        bfrag pL0 = *(const bfrag*)&bPL[arow * LSTR + (q << 3)];
        bfrag pH1, pL1;
        if (c < 4) {
            pH1 = *(const bfrag*)&bPH[arow * LSTR + 32 + (q << 3)];
            pL1 = *(const bfrag*)&bPL[arow * LSTR + 32 + (q << 3)];
        }
        #pragma unroll
        for (int et = 0; et < 4; ++et) {
            const int erow = (et << 4) + l15;
            bfrag cH0 = *(const bfrag*)&bQH[erow * LSTR + (q << 3)];
            bfrag cL0 = *(const bfrag*)&bQL[erow * LSTR + (q << 3)];
            f32x4 a = oacc[et];
            a = MFMA(pH0, cL0, a);
            a = MFMA(pL0, cH0, a);
            a = MFMA(pH0, cH0, a);
            if (c < 4) {
                bfrag cH1 = *(const bfrag*)&bQH[erow * LSTR + 32 + (q << 3)];
                bfrag cL1 = *(const bfrag*)&bQL[erow * LSTR + 32 + (q << 3)];
                a = MFMA(pH1, cL1, a);
                a = MFMA(pL1, cH1, a);
                a = MFMA(pH1, cH1, a);
            }
            oacc[et] = a;
        }
    }

    float* ob = outp + ((size_t)hd * NN + n0) * DD;
    #pragma unroll
    for (int et = 0; et < 4; ++et)
        #pragma unroll
        for (int reg = 0; reg < 4; ++reg)
            ob[((w << 4) + (q << 2) + reg) * DD + (et << 4) + l15] = oacc[et][reg] * dinv[reg];
}

// ---------------------------------------------------------------------------
extern "C" void kernel_launch(void* const* d_in, const int* in_sizes, int n_in,
                              void* d_out, int out_size, void* d_ws, size_t ws_size,
                              hipStream_t stream)
{
    const float* q = (const float*)d_in[0];
    const float* k = (const float*)d_in[1];
    const float* v = (const float*)d_in[2];
    const float* proj = (const float*)d_in[3];
    float* out = (float*)d_out;
    char* ws = (char*)d_ws;

    ushort* gH  = (ushort*)(ws);                    // 32*64*320*2 = 1,310,720 B
    ushort* gL  = (ushort*)(ws + 1310720);          // 1,310,720 B
    float*  vsm = (float*)(ws + 2621440);           // 8,192 B
    ushort* pH  = (ushort*)(ws + 2629632);          // 34,816 B
    ushort* pL  = (ushort*)(ws + 2664448);          // 34,816 B
    float*  kcF = (float*)(ws + 2699264);           // 34,816 B
    float*  ctxP= (float*)(ws + 2734080);           // 512*272*64*4 = 35,651,584 B
    float*  kcP = (float*)(ws + 38385664);          // 557,056 B
    float*  pmax= (float*)(ws + 38942720);          // 2,048 B

    hipMemsetAsync(ws, 0, 2629632, stream);         // gH, gL, vsum

    proj_split<<<dim3(17), 256, 0, stream>>>(proj, pH, pL);
    kpass<<<dim3(16, 32), 256, 0, stream>>>(k, v, pH, pL, ctxP, kcP, pmax, vsm);
    ctx_reduce<<<dim3(17, 32), 256, 0, stream>>>(ctxP, kcP, vsm, pmax, gH, gL, kcF);
    qpass<<<dim3(64, 32), 256, 0, stream>>>(q, pH, pL, gH, gL, kcF, out);
}